// Round 1
// baseline (2181.120 us; speedup 1.0000x reference)
//
#include <hip/hip_runtime.h>
#include <math.h>

#define D_MODEL 1024
#define NHEAD   16
#define DKH     64
#define DFF_    4096
#define BB      2
#define SS      2048
#define MTOT    (BB*SS)
#define EPSLN   1e-6f
#define NEG_SLOPE 0.01f

// ---------------------------------------------------------------------------
// Generic fp32 GEMM: C[M,N] = A[M,K] @ W[K,N] + bias[N], optional LeakyReLU.
// 64x64 tile, BK=16, 256 threads, 4x4 accumulators per thread.
// ---------------------------------------------------------------------------
template<int ACT>
__global__ __launch_bounds__(256)
void gemm_bias(const float* __restrict__ A, const float* __restrict__ W,
               const float* __restrict__ bias, float* __restrict__ C,
               int M, int N, int K)
{
    __shared__ float As[16][68];   // [k][row]; stride 68: float4-aligned, 2-way banks max
    __shared__ float Bs[16][68];   // [k][col]

    const int tid = threadIdx.x;
    const int tx  = tid & 15;      // 0..15 -> col group
    const int ty  = tid >> 4;      // 0..15 -> row group
    const int row0 = blockIdx.y * 64;
    const int col0 = blockIdx.x * 64;

    float acc[4][4] = {};

    // A-load mapping: thread -> (row r=tid>>2, 4 consecutive k at (tid&3)*4)
    const int ar = tid >> 2;
    const int ak = (tid & 3) * 4;
    // B-load mapping: thread -> (k=tid>>4, 4 consecutive cols at (tid&15)*4)
    const int bk = tid >> 4;
    const int bc = (tid & 15) * 4;

    for (int k0 = 0; k0 < K; k0 += 16) {
        float4 av = *(const float4*)&A[(size_t)(row0 + ar) * K + k0 + ak];
        float4 bv = *(const float4*)&W[(size_t)(k0 + bk) * N + col0 + bc];
        As[ak + 0][ar] = av.x;
        As[ak + 1][ar] = av.y;
        As[ak + 2][ar] = av.z;
        As[ak + 3][ar] = av.w;
        *(float4*)&Bs[bk][bc] = bv;
        __syncthreads();
        #pragma unroll
        for (int kk = 0; kk < 16; ++kk) {
            float4 a4 = *(const float4*)&As[kk][ty * 4];
            float4 b4 = *(const float4*)&Bs[kk][tx * 4];
            float a_[4] = {a4.x, a4.y, a4.z, a4.w};
            float b_[4] = {b4.x, b4.y, b4.z, b4.w};
            #pragma unroll
            for (int i = 0; i < 4; ++i)
                #pragma unroll
                for (int j = 0; j < 4; ++j)
                    acc[i][j] = fmaf(a_[i], b_[j], acc[i][j]);
        }
        __syncthreads();
    }

    float4 bb = *(const float4*)&bias[col0 + tx * 4];
    #pragma unroll
    for (int i = 0; i < 4; ++i) {
        int rr = row0 + ty * 4 + i;
        float4 vv;
        vv.x = acc[i][0] + bb.x;
        vv.y = acc[i][1] + bb.y;
        vv.z = acc[i][2] + bb.z;
        vv.w = acc[i][3] + bb.w;
        if (ACT == 1) {
            vv.x = vv.x > 0.f ? vv.x : NEG_SLOPE * vv.x;
            vv.y = vv.y > 0.f ? vv.y : NEG_SLOPE * vv.y;
            vv.z = vv.z > 0.f ? vv.z : NEG_SLOPE * vv.z;
            vv.w = vv.w > 0.f ? vv.w : NEG_SLOPE * vv.w;
        }
        *(float4*)&C[(size_t)rr * N + col0 + tx * 4] = vv;
    }
}

// ---------------------------------------------------------------------------
// Flash-style attention, fp32. Q,K,V,O are [B*S, D] with head h in columns
// h*64..h*64+63. One block per (query-tile of 64, b*H+h). Online softmax in
// registers; quad (4-thread) shfl_xor reductions per query row.
// Thread t owns row r=t>>2, col group cq=(t&3)*16 of the 64x64 output tile.
// ---------------------------------------------------------------------------
__global__ __launch_bounds__(256)
void attention(const float* __restrict__ Qm, const float* __restrict__ Km,
               const float* __restrict__ Vm, float* __restrict__ Om)
{
    __shared__ float Qt[64][68];    // [row][d], pre-scaled by 1/sqrt(DK)
    __shared__ float X [64][68];    // K raw, later V  [key][d]
    __shared__ float KtT[64][68];   // [d][key]
    __shared__ float Pt[64][68];    // probs [row][key]

    const int tid   = threadIdx.x;
    const int qtile = blockIdx.x;
    const int bh    = blockIdx.y;
    const int b     = bh >> 4;
    const int h     = bh & 15;
    const size_t rowbase = (size_t)b * SS;
    const int colbase    = h * DKH;

    const int r  = tid >> 2;
    const int cq = (tid & 3) * 16;
    const int q0 = qtile * 64;

    #pragma unroll
    for (int i = 0; i < 16; ++i) {
        int l = tid + i * 256;
        int rr = l >> 6, d = l & 63;
        Qt[rr][d] = Qm[(rowbase + q0 + rr) * D_MODEL + colbase + d] * 0.125f;
    }

    float m_run = -__builtin_inff();
    float l_run = 0.f;
    float o[16];
    #pragma unroll
    for (int i = 0; i < 16; ++i) o[i] = 0.f;

    for (int kt = 0; kt < SS / 64; ++kt) {
        const int k0 = kt * 64;
        __syncthreads();   // prev iter done with X/Pt (covers Qt store on kt=0)
        #pragma unroll
        for (int i = 0; i < 16; ++i) {
            int l = tid + i * 256;
            int rr = l >> 6, d = l & 63;
            X[rr][d] = Km[(rowbase + k0 + rr) * D_MODEL + colbase + d];
        }
        __syncthreads();
        #pragma unroll
        for (int i = 0; i < 16; ++i) {
            int l = tid + i * 256;
            int rr = l >> 6, d = l & 63;
            KtT[d][rr] = X[rr][d];
        }
        __syncthreads();
        // load V into X (not read until after next barrier)
        #pragma unroll
        for (int i = 0; i < 16; ++i) {
            int l = tid + i * 256;
            int rr = l >> 6, d = l & 63;
            X[rr][d] = Vm[(rowbase + k0 + rr) * D_MODEL + colbase + d];
        }
        // scores: sc[j] = sum_d Qt[r][d] * K[k0+cq+j][d]
        float sc[16];
        #pragma unroll
        for (int j = 0; j < 16; ++j) sc[j] = 0.f;
        #pragma unroll 4
        for (int d = 0; d < 64; ++d) {
            float qv = Qt[r][d];
            const float4* kp = (const float4*)&KtT[d][cq];
            float kv[16];
            *(float4*)&kv[0]  = kp[0];
            *(float4*)&kv[4]  = kp[1];
            *(float4*)&kv[8]  = kp[2];
            *(float4*)&kv[12] = kp[3];
            #pragma unroll
            for (int j = 0; j < 16; ++j) sc[j] = fmaf(qv, kv[j], sc[j]);
        }
        // online softmax: reduce across the 4 threads of this row's quad
        float tmax = sc[0];
        #pragma unroll
        for (int j = 1; j < 16; ++j) tmax = fmaxf(tmax, sc[j]);
        tmax = fmaxf(tmax, __shfl_xor(tmax, 1, 64));
        tmax = fmaxf(tmax, __shfl_xor(tmax, 2, 64));
        float m_new = fmaxf(m_run, tmax);
        float alpha = __expf(m_run - m_new);
        float lsum = 0.f;
        #pragma unroll
        for (int j = 0; j < 16; ++j) { sc[j] = __expf(sc[j] - m_new); lsum += sc[j]; }
        lsum += __shfl_xor(lsum, 1, 64);
        lsum += __shfl_xor(lsum, 2, 64);
        l_run = l_run * alpha + lsum;
        m_run = m_new;
        #pragma unroll
        for (int j = 0; j < 4; ++j) {
            float4 pv = {sc[4*j+0], sc[4*j+1], sc[4*j+2], sc[4*j+3]};
            *(float4*)&Pt[r][cq + 4*j] = pv;
        }
        #pragma unroll
        for (int i = 0; i < 16; ++i) o[i] *= alpha;
        __syncthreads();   // Pt + V(X) ready for everyone
        // O update: o[cc] += sum_j Pt[r][j] * V[j][cq+cc]
        #pragma unroll 4
        for (int j = 0; j < 64; ++j) {
            float p = Pt[r][j];
            const float4* vp = (const float4*)&X[j][cq];
            float vv[16];
            *(float4*)&vv[0]  = vp[0];
            *(float4*)&vv[4]  = vp[1];
            *(float4*)&vv[8]  = vp[2];
            *(float4*)&vv[12] = vp[3];
            #pragma unroll
            for (int cc = 0; cc < 16; ++cc) o[cc] = fmaf(p, vv[cc], o[cc]);
        }
    }

    float inv_l = 1.0f / l_run;
    float* orow = Om + (rowbase + q0 + r) * D_MODEL + colbase + cq;
    #pragma unroll
    for (int j = 0; j < 4; ++j) {
        float4 ov = {o[4*j+0] * inv_l, o[4*j+1] * inv_l,
                     o[4*j+2] * inv_l, o[4*j+3] * inv_l};
        *(float4*)&orow[4*j] = ov;
    }
}

// ---------------------------------------------------------------------------
// out[row] = LayerNorm(A[row] + B[row]) * g + beta.  One block per row.
// ---------------------------------------------------------------------------
__global__ __launch_bounds__(256)
void add_ln(const float* __restrict__ A, const float* __restrict__ B,
            const float* __restrict__ g, const float* __restrict__ beta,
            float* __restrict__ out)
{
    __shared__ float red[8];
    const int row = blockIdx.x;
    const int tid = threadIdx.x;
    const float4* a4 = (const float4*)(A + (size_t)row * D_MODEL);
    const float4* b4 = (const float4*)(B + (size_t)row * D_MODEL);
    float4 va = a4[tid];
    float4 vb = b4[tid];
    float4 v  = {va.x + vb.x, va.y + vb.y, va.z + vb.z, va.w + vb.w};
    float s  = v.x + v.y + v.z + v.w;
    float sq = v.x*v.x + v.y*v.y + v.z*v.z + v.w*v.w;
    #pragma unroll
    for (int off = 32; off > 0; off >>= 1) {
        s  += __shfl_down(s,  off, 64);
        sq += __shfl_down(sq, off, 64);
    }
    const int wv = tid >> 6;
    if ((tid & 63) == 0) { red[wv] = s; red[4 + wv] = sq; }
    __syncthreads();
    float st  = red[0] + red[1] + red[2] + red[3];
    float sqt = red[4] + red[5] + red[6] + red[7];
    float mu   = st * (1.0f / D_MODEL);
    float var  = sqt * (1.0f / D_MODEL) - mu * mu;
    float rstd = rsqrtf(var + EPSLN);
    float4 gv  = ((const float4*)g)[tid];
    float4 bt  = ((const float4*)beta)[tid];
    float4 ov;
    ov.x = (v.x - mu) * rstd * gv.x + bt.x;
    ov.y = (v.y - mu) * rstd * gv.y + bt.y;
    ov.z = (v.z - mu) * rstd * gv.z + bt.z;
    ov.w = (v.w - mu) * rstd * gv.w + bt.w;
    ((float4*)(out + (size_t)row * D_MODEL))[tid] = ov;
}

// ---------------------------------------------------------------------------
extern "C" void kernel_launch(void* const* d_in, const int* in_sizes, int n_in,
                              void* d_out, int out_size, void* d_ws, size_t ws_size,
                              hipStream_t stream) {
    const float* x     = (const float*)d_in[0];
    const float* wq    = (const float*)d_in[1];
    const float* bq    = (const float*)d_in[2];
    const float* wk    = (const float*)d_in[3];
    const float* bk    = (const float*)d_in[4];
    const float* wv    = (const float*)d_in[5];
    const float* bv    = (const float*)d_in[6];
    const float* wo    = (const float*)d_in[7];
    const float* bo    = (const float*)d_in[8];
    const float* g1    = (const float*)d_in[9];
    const float* b1    = (const float*)d_in[10];
    const float* w_ff1 = (const float*)d_in[11];
    const float* b_ff1 = (const float*)d_in[12];
    const float* w_ff2 = (const float*)d_in[13];
    const float* b_ff2 = (const float*)d_in[14];
    const float* g2    = (const float*)d_in[15];
    const float* b2    = (const float*)d_in[16];
    float* out = (float*)d_out;

    float* ws  = (float*)d_ws;
    float* Qb  = ws;                       // 4096*1024
    float* Kb  = ws + 4194304;
    float* Vb  = ws + 8388608;
    float* Ctx = ws + 12582912;
    float* FF1 = ws + 16777216;            // 4096*4096
    float* AttnOut = Qb;                   // reuse (Q dead after attention)
    float* Hbuf    = Kb;                   // reuse (K dead after attention)
    float* FF2     = Vb;                   // reuse (V dead after attention)

    dim3 blk(256);
    gemm_bias<0><<<dim3(16, 64), blk, 0, stream>>>(x, wq, bq, Qb, MTOT, D_MODEL, D_MODEL);
    gemm_bias<0><<<dim3(16, 64), blk, 0, stream>>>(x, wk, bk, Kb, MTOT, D_MODEL, D_MODEL);
    gemm_bias<0><<<dim3(16, 64), blk, 0, stream>>>(x, wv, bv, Vb, MTOT, D_MODEL, D_MODEL);
    attention<<<dim3(SS / 64, BB * NHEAD), blk, 0, stream>>>(Qb, Kb, Vb, Ctx);
    gemm_bias<0><<<dim3(16, 64), blk, 0, stream>>>(Ctx, wo, bo, AttnOut, MTOT, D_MODEL, D_MODEL);
    add_ln<<<MTOT, blk, 0, stream>>>(AttnOut, x, g1, b1, Hbuf);
    gemm_bias<1><<<dim3(64, 64), blk, 0, stream>>>(Hbuf, w_ff1, b_ff1, FF1, MTOT, DFF_, D_MODEL);
    gemm_bias<0><<<dim3(16, 64), blk, 0, stream>>>(FF1, w_ff2, b_ff2, FF2, MTOT, D_MODEL, DFF_);
    add_ln<<<MTOT, blk, 0, stream>>>(FF2, Hbuf, g2, b2, out);
}

// Round 2
// 493.558 us; speedup vs baseline: 4.4192x; 4.4192x over previous
//
#include <hip/hip_runtime.h>
#include <math.h>

#define D_MODEL 1024
#define NHEAD   16
#define DKH     64
#define DFF_    4096
#define BB      2
#define SS      2048
#define MTOT    (BB*SS)
#define EPSLN   1e-6f
#define NEG_SLOPE 0.01f

typedef unsigned short u16;
typedef unsigned int   u32;
typedef __bf16 bf16x8 __attribute__((ext_vector_type(8)));
typedef float  f32x4  __attribute__((ext_vector_type(4)));
typedef u16    u16x4  __attribute__((ext_vector_type(4)));

__device__ __forceinline__ u16 f2bf(float f) {
    u32 u = __float_as_uint(f);
    u = (u + 0x7fffu + ((u >> 16) & 1u)) >> 16;
    return (u16)u;
}

__device__ __forceinline__ void gload_lds16(const u16* g, u16* l) {
    __builtin_amdgcn_global_load_lds(
        (const __attribute__((address_space(1))) u32*)g,
        (__attribute__((address_space(3))) u32*)l,
        16, 0, 0);
}

// ---------------------------------------------------------------------------
// fp32 -> bf16 plain convert (n multiple of 1024)
// ---------------------------------------------------------------------------
__global__ __launch_bounds__(256)
void f32_to_bf16(const float* __restrict__ in, u16* __restrict__ out) {
    int i = blockIdx.x * 256 + threadIdx.x;
    float4 v = ((const float4*)in)[i];
    u16x4 o = { f2bf(v.x), f2bf(v.y), f2bf(v.z), f2bf(v.w) };
    ((u16x4*)out)[i] = o;
}

// ---------------------------------------------------------------------------
// W [K][N] fp32  ->  WT [N][K] bf16 (rows offset by out_row_off)
// ---------------------------------------------------------------------------
__global__ __launch_bounds__(256)
void transpose_w_bf16(const float* __restrict__ W, u16* __restrict__ WT,
                      int K, int N, int out_stride, int out_row_off)
{
    __shared__ u16 T[64 * 72];
    const int t  = threadIdx.x;
    const int n0 = blockIdx.x * 64;
    const int k0 = blockIdx.y * 64;
    #pragma unroll
    for (int i = 0; i < 4; ++i) {
        int r = i * 16 + (t >> 4);          // k
        int c = (t & 15) * 4;               // n
        float4 v = *(const float4*)&W[(size_t)(k0 + r) * N + n0 + c];
        T[(c + 0) * 72 + r] = f2bf(v.x);
        T[(c + 1) * 72 + r] = f2bf(v.y);
        T[(c + 2) * 72 + r] = f2bf(v.z);
        T[(c + 3) * 72 + r] = f2bf(v.w);
    }
    __syncthreads();
    #pragma unroll
    for (int i = 0; i < 4; ++i) {
        int nr = i * 16 + (t >> 4);
        int kc = (t & 15) * 4;
        u16x4 o = { T[nr*72 + kc], T[nr*72 + kc + 1], T[nr*72 + kc + 2], T[nr*72 + kc + 3] };
        *(u16x4*)&WT[(size_t)(out_row_off + n0 + nr) * out_stride + k0 + kc] = o;
    }
}

// ---------------------------------------------------------------------------
// V part of QKV [4096][3072] (cols 2048+) -> Vt [B*H*64][S] bf16
// ---------------------------------------------------------------------------
__global__ __launch_bounds__(256)
void transpose_v(const u16* __restrict__ QKV, u16* __restrict__ Vt)
{
    __shared__ u16 T[64 * 72];
    const int t  = threadIdx.x;
    const int s0 = blockIdx.x * 64;
    const int bh = blockIdx.y;
    const int b  = bh >> 4, h = bh & 15;
    #pragma unroll
    for (int i = 0; i < 2; ++i) {
        int r = i * 32 + (t >> 3);       // s
        int c = (t & 7) * 8;             // d
        bf16x8 v = *(const bf16x8*)(QKV + ((size_t)b * SS + s0 + r) * 3072 + 2048 + h * 64 + c);
        #pragma unroll
        for (int j = 0; j < 8; ++j) T[(c + j) * 72 + r] = ((const u16*)&v)[j];
    }
    __syncthreads();
    #pragma unroll
    for (int i = 0; i < 2; ++i) {
        int d  = i * 32 + (t >> 3);
        int kc = (t & 7) * 8;
        *(bf16x8*)(Vt + ((size_t)bh * 64 + d) * SS + s0 + kc) = *(const bf16x8*)&T[d * 72 + kc];
    }
}

__global__ __launch_bounds__(256)
void concat_bias(const float* __restrict__ a, const float* __restrict__ b,
                 const float* __restrict__ c, float* __restrict__ out) {
    int i = blockIdx.x * 256 + threadIdx.x;
    out[i] = (i < 1024) ? a[i] : ((i < 2048) ? b[i - 1024] : c[i - 2048]);
}

// ---------------------------------------------------------------------------
// bf16 MFMA GEMM: C[M,N] = A[M,K] @ BT[N,K]^T + bias.
// 128x128 tile, BK=32, 4 waves, 16x16x32 mfma, global_load_lds staging with
// XOR quad swizzle (2-way max bank aliasing on ds_read_b128).
// EPI: 0 = bf16 out, 1 = bf16 + LeakyReLU, 2 = f32 out
// ---------------------------------------------------------------------------
template<int EPI>
__global__ __launch_bounds__(256)
void gemm_bf16(const u16* __restrict__ A, const u16* __restrict__ BT,
               const float* __restrict__ bias, void* __restrict__ Cout,
               int M, int N, int K)
{
    __shared__ u16 As[128 * 32];
    __shared__ u16 Bs[128 * 32];
    const int tid  = threadIdx.x;
    const int w    = tid >> 6;
    const int lane = tid & 63;
    const int lm   = lane & 15;
    const int lq   = lane >> 4;
    const int row0 = blockIdx.y * 128;
    const int col0 = blockIdx.x * 128;
    const int wrow = (w >> 1) * 64;
    const int wcol = (w & 1) * 64;

    f32x4 acc[4][4] = {};

    const int r_l  = lane >> 2;                          // 0..15 within 16-row slab
    const int q_sw = (lane & 3) ^ ((lane >> 3) & 3);     // swizzled k-quad to load
    const u16* a_src = A  + (size_t)(row0 + w * 32 + r_l) * K + q_sw * 8;
    const u16* b_src = BT + (size_t)(col0 + w * 32 + r_l) * K + q_sw * 8;
    u16* a_dst = &As[(w * 32) * 32];
    u16* b_dst = &Bs[(w * 32) * 32];
    const size_t stepA = (size_t)16 * K;

    const int pos = lq ^ ((lm >> 1) & 3);                // read-side swizzle
    const u16* a_rd = &As[(wrow + lm) * 32 + pos * 8];
    const u16* b_rd = &Bs[(wcol + lm) * 32 + pos * 8];

    for (int k0 = 0; k0 < K; k0 += 32) {
        gload_lds16(a_src + k0,         a_dst);
        gload_lds16(a_src + k0 + stepA, a_dst + 16 * 32);
        gload_lds16(b_src + k0,         b_dst);
        gload_lds16(b_src + k0 + stepA, b_dst + 16 * 32);
        __syncthreads();
        bf16x8 av[4], bv[4];
        #pragma unroll
        for (int m = 0; m < 4; ++m) av[m] = *(const bf16x8*)(a_rd + m * 16 * 32);
        #pragma unroll
        for (int n = 0; n < 4; ++n) bv[n] = *(const bf16x8*)(b_rd + n * 16 * 32);
        #pragma unroll
        for (int m = 0; m < 4; ++m)
            #pragma unroll
            for (int n = 0; n < 4; ++n)
                acc[m][n] = __builtin_amdgcn_mfma_f32_16x16x32_bf16(av[m], bv[n], acc[m][n], 0, 0, 0);
        __syncthreads();
    }

    float bz[4];
    #pragma unroll
    for (int n = 0; n < 4; ++n) bz[n] = bias[col0 + wcol + n * 16 + lm];

    #pragma unroll
    for (int m = 0; m < 4; ++m) {
        #pragma unroll
        for (int e = 0; e < 4; ++e) {
            int row = row0 + wrow + m * 16 + lq * 4 + e;
            #pragma unroll
            for (int n = 0; n < 4; ++n) {
                int col = col0 + wcol + n * 16 + lm;
                float v = acc[m][n][e] + bz[n];
                if (EPI == 1) v = v > 0.f ? v : NEG_SLOPE * v;
                if (EPI == 2) ((float*)Cout)[(size_t)row * N + col] = v;
                else          ((u16*)Cout)[(size_t)row * N + col]  = f2bf(v);
            }
        }
    }
}

// ---------------------------------------------------------------------------
// Flash attention, bf16 MFMA. QKV [4096][3072], Vt [B*H*64][S], ctx [4096][1024].
// Block: 256 thr, 64-query tile; wave w owns q rows w*16..w*16+15.
// ---------------------------------------------------------------------------
__global__ __launch_bounds__(256)
void attn_mfma(const u16* __restrict__ QKV, const u16* __restrict__ Vt,
               u16* __restrict__ ctx)
{
    __shared__ u16 Qs[64 * 72];
    __shared__ u16 Ks[64 * 72];
    __shared__ u16 Vs[64 * 72];   // [d][key]
    __shared__ u16 Ps[64 * 72];
    const int tid = threadIdx.x, w = tid >> 6, lane = tid & 63;
    const int lm = lane & 15, lq = lane >> 4;
    const int q0 = blockIdx.x * 64;
    const int bh = blockIdx.y;
    const int b  = bh >> 4, h = bh & 15;
    const size_t row_b = (size_t)b * SS;
    const int ccol = h * DKH;

    const int sr = tid >> 3;          // 0..31
    const int sc = (tid & 7) * 8;     // 0..56

    #pragma unroll
    for (int i = 0; i < 2; ++i) {
        int r = i * 32 + sr;
        *(bf16x8*)&Qs[r * 72 + sc] =
            *(const bf16x8*)(QKV + (row_b + q0 + r) * 3072 + ccol + sc);
    }
    __syncthreads();
    bf16x8 aq0 = *(const bf16x8*)&Qs[(w * 16 + lm) * 72 + lq * 8];
    bf16x8 aq1 = *(const bf16x8*)&Qs[(w * 16 + lm) * 72 + 32 + lq * 8];

    float m_run[4], l_run[4];
    f32x4 o[4] = {};
    #pragma unroll
    for (int e = 0; e < 4; ++e) { m_run[e] = -1e30f; l_run[e] = 0.f; }

    for (int kt = 0; kt < SS / 64; ++kt) {
        const int k0 = kt * 64;
        __syncthreads();   // Ks/Vs free (prev iter consumed)
        #pragma unroll
        for (int i = 0; i < 2; ++i) {
            int r = i * 32 + sr;
            *(bf16x8*)&Ks[r * 72 + sc] =
                *(const bf16x8*)(QKV + (row_b + k0 + r) * 3072 + 1024 + ccol + sc);
            *(bf16x8*)&Vs[r * 72 + sc] =
                *(const bf16x8*)(Vt + ((size_t)bh * 64 + r) * SS + k0 + sc);
        }
        __syncthreads();

        f32x4 s[4] = {};
        #pragma unroll
        for (int n = 0; n < 4; ++n) {
            bf16x8 bk0 = *(const bf16x8*)&Ks[(n * 16 + lm) * 72 + lq * 8];
            bf16x8 bk1 = *(const bf16x8*)&Ks[(n * 16 + lm) * 72 + 32 + lq * 8];
            s[n] = __builtin_amdgcn_mfma_f32_16x16x32_bf16(aq0, bk0, s[n], 0, 0, 0);
            s[n] = __builtin_amdgcn_mfma_f32_16x16x32_bf16(aq1, bk1, s[n], 0, 0, 0);
        }

        float al[4];
        #pragma unroll
        for (int e = 0; e < 4; ++e) {
            float mx = fmaxf(fmaxf(s[0][e], s[1][e]), fmaxf(s[2][e], s[3][e]));
            mx = fmaxf(mx, __shfl_xor(mx, 1, 64));
            mx = fmaxf(mx, __shfl_xor(mx, 2, 64));
            mx = fmaxf(mx, __shfl_xor(mx, 4, 64));
            mx = fmaxf(mx, __shfl_xor(mx, 8, 64));
            mx *= 0.125f;
            float mnew = fmaxf(m_run[e], mx);
            float pv[4], psum = 0.f;
            #pragma unroll
            for (int n = 0; n < 4; ++n) {
                pv[n] = __expf(s[n][e] * 0.125f - mnew);
                psum += pv[n];
            }
            psum += __shfl_xor(psum, 1, 64);
            psum += __shfl_xor(psum, 2, 64);
            psum += __shfl_xor(psum, 4, 64);
            psum += __shfl_xor(psum, 8, 64);
            al[e] = __expf(m_run[e] - mnew);
            l_run[e] = l_run[e] * al[e] + psum;
            m_run[e] = mnew;
            #pragma unroll
            for (int n = 0; n < 4; ++n)
                Ps[(w * 16 + lq * 4 + e) * 72 + n * 16 + lm] = f2bf(pv[n]);
        }
        #pragma unroll
        for (int n = 0; n < 4; ++n)
            #pragma unroll
            for (int e = 0; e < 4; ++e) o[n][e] *= al[e];

        __syncthreads();   // Ps visible
        bf16x8 ap0 = *(const bf16x8*)&Ps[(w * 16 + lm) * 72 + lq * 8];
        bf16x8 ap1 = *(const bf16x8*)&Ps[(w * 16 + lm) * 72 + 32 + lq * 8];
        #pragma unroll
        for (int n = 0; n < 4; ++n) {
            bf16x8 bv0 = *(const bf16x8*)&Vs[(n * 16 + lm) * 72 + lq * 8];
            bf16x8 bv1 = *(const bf16x8*)&Vs[(n * 16 + lm) * 72 + 32 + lq * 8];
            o[n] = __builtin_amdgcn_mfma_f32_16x16x32_bf16(ap0, bv0, o[n], 0, 0, 0);
            o[n] = __builtin_amdgcn_mfma_f32_16x16x32_bf16(ap1, bv1, o[n], 0, 0, 0);
        }
    }

    #pragma unroll
    for (int e = 0; e < 4; ++e) {
        float inv = 1.0f / l_run[e];
        int row = q0 + w * 16 + lq * 4 + e;
        u16* dst = ctx + (row_b + row) * D_MODEL + ccol;
        #pragma unroll
        for (int n = 0; n < 4; ++n)
            dst[n * 16 + lm] = f2bf(o[n][e] * inv);
    }
}

// ---------------------------------------------------------------------------
// out = LayerNorm(A + B) * g + beta; optional bf16 mirror for next GEMM.
// ---------------------------------------------------------------------------
template<int DUAL>
__global__ __launch_bounds__(256)
void add_ln(const float* __restrict__ A, const float* __restrict__ B,
            const float* __restrict__ g, const float* __restrict__ beta,
            float* __restrict__ out, u16* __restrict__ out_bf)
{
    __shared__ float red[8];
    const int row = blockIdx.x;
    const int tid = threadIdx.x;
    float4 va = ((const float4*)(A + (size_t)row * D_MODEL))[tid];
    float4 vb = ((const float4*)(B + (size_t)row * D_MODEL))[tid];
    float4 v  = { va.x + vb.x, va.y + vb.y, va.z + vb.z, va.w + vb.w };
    float s  = v.x + v.y + v.z + v.w;
    float sq = v.x*v.x + v.y*v.y + v.z*v.z + v.w*v.w;
    #pragma unroll
    for (int off = 32; off > 0; off >>= 1) {
        s  += __shfl_down(s,  off, 64);
        sq += __shfl_down(sq, off, 64);
    }
    const int wv = tid >> 6;
    if ((tid & 63) == 0) { red[wv] = s; red[4 + wv] = sq; }
    __syncthreads();
    float st  = red[0] + red[1] + red[2] + red[3];
    float sqt = red[4] + red[5] + red[6] + red[7];
    float mu   = st * (1.0f / D_MODEL);
    float var  = sqt * (1.0f / D_MODEL) - mu * mu;
    float rstd = rsqrtf(var + EPSLN);
    float4 gv = ((const float4*)g)[tid];
    float4 bt = ((const float4*)beta)[tid];
    float4 ov;
    ov.x = (v.x - mu) * rstd * gv.x + bt.x;
    ov.y = (v.y - mu) * rstd * gv.y + bt.y;
    ov.z = (v.z - mu) * rstd * gv.z + bt.z;
    ov.w = (v.w - mu) * rstd * gv.w + bt.w;
    ((float4*)(out + (size_t)row * D_MODEL))[tid] = ov;
    if (DUAL) {
        u16x4 ob = { f2bf(ov.x), f2bf(ov.y), f2bf(ov.z), f2bf(ov.w) };
        ((u16x4*)(out_bf + (size_t)row * D_MODEL))[tid] = ob;
    }
}

// ---------------------------------------------------------------------------
extern "C" void kernel_launch(void* const* d_in, const int* in_sizes, int n_in,
                              void* d_out, int out_size, void* d_ws, size_t ws_size,
                              hipStream_t stream) {
    const float* x     = (const float*)d_in[0];
    const float* wq    = (const float*)d_in[1];
    const float* bq    = (const float*)d_in[2];
    const float* wk    = (const float*)d_in[3];
    const float* bk    = (const float*)d_in[4];
    const float* wv    = (const float*)d_in[5];
    const float* bv    = (const float*)d_in[6];
    const float* wo    = (const float*)d_in[7];
    const float* bo    = (const float*)d_in[8];
    const float* g1    = (const float*)d_in[9];
    const float* b1    = (const float*)d_in[10];
    const float* w_ff1 = (const float*)d_in[11];
    const float* b_ff1 = (const float*)d_in[12];
    const float* w_ff2 = (const float*)d_in[13];
    const float* b_ff2 = (const float*)d_in[14];
    const float* g2    = (const float*)d_in[15];
    const float* b2    = (const float*)d_in[16];
    float* out = (float*)d_out;

    char* W = (char*)d_ws;
    u16*   x_bf    = (u16*)(W + 0);             // 8.4 MB  (later: ctx)
    u16*   wqkvT   = (u16*)(W + 8388608);       // 6.3 MB
    u16*   woT     = (u16*)(W + 14680064);      // 2.1 MB
    u16*   wff1T   = (u16*)(W + 16777216);      // 8.4 MB
    u16*   wff2T   = (u16*)(W + 25165824);      // 8.4 MB
    u16*   QKV     = (u16*)(W + 33554432);      // 25.2 MB (later: ff1 w/ next region)
    u16*   VtG     = (u16*)(W + 58720256);      // 8.4 MB
    float* attnout = (float*)(W + 67108864);    // 16.8 MB (later: ff2)
    float* h_f     = (float*)(W + 83886080);    // 16.8 MB
    u16*   h_bf    = (u16*)(W + 100663296);     // 8.4 MB
    float* qkv_bias= (float*)(W + 109051904);   // 12 KB
    u16*   ctx     = x_bf;
    u16*   ff1_bf  = QKV;
    float* ff2     = attnout;

    dim3 blk(256);
    // --- input conversions ---
    f32_to_bf16<<<4096, blk, 0, stream>>>(x, x_bf);
    transpose_w_bf16<<<dim3(16, 16), blk, 0, stream>>>(wq, wqkvT, 1024, 1024, 1024, 0);
    transpose_w_bf16<<<dim3(16, 16), blk, 0, stream>>>(wk, wqkvT, 1024, 1024, 1024, 1024);
    transpose_w_bf16<<<dim3(16, 16), blk, 0, stream>>>(wv, wqkvT, 1024, 1024, 1024, 2048);
    transpose_w_bf16<<<dim3(16, 16), blk, 0, stream>>>(wo, woT, 1024, 1024, 1024, 0);
    transpose_w_bf16<<<dim3(64, 16), blk, 0, stream>>>(w_ff1, wff1T, 1024, 4096, 1024, 0);
    transpose_w_bf16<<<dim3(16, 64), blk, 0, stream>>>(w_ff2, wff2T, 4096, 1024, 4096, 0);
    concat_bias<<<12, blk, 0, stream>>>(bq, bk, bv, qkv_bias);

    // --- QKV projection (fused) ---
    gemm_bf16<0><<<dim3(24, 32), blk, 0, stream>>>(x_bf, wqkvT, qkv_bias, QKV, MTOT, 3072, 1024);
    // --- V transpose per head ---
    transpose_v<<<dim3(32, 32), blk, 0, stream>>>(QKV, VtG);
    // --- attention ---
    attn_mfma<<<dim3(32, 32), blk, 0, stream>>>(QKV, VtG, ctx);
    // --- output projection ---
    gemm_bf16<2><<<dim3(8, 32), blk, 0, stream>>>(ctx, woT, bo, attnout, MTOT, 1024, 1024);
    // --- residual + LN1 ---
    add_ln<1><<<MTOT, blk, 0, stream>>>(attnout, x, g1, b1, h_f, h_bf);
    // --- FFN ---
    gemm_bf16<1><<<dim3(32, 32), blk, 0, stream>>>(h_bf, wff1T, b_ff1, ff1_bf, MTOT, DFF_, 1024);
    gemm_bf16<2><<<dim3(8, 32), blk, 0, stream>>>(ff1_bf, wff2T, b_ff2, ff2, MTOT, 1024, DFF_);
    // --- residual + LN2 ---
    add_ln<0><<<MTOT, blk, 0, stream>>>(ff2, h_f, g2, b2, out, nullptr);
}